// Round 9
// baseline (326.735 us; speedup 1.0000x reference)
//
#include <hip/hip_runtime.h>
#include <hip/hip_bf16.h>
#include <stdint.h>

#define BB   8
#define CCH  128
#define HH   256
#define WWD  256
#define OCC  64
#define HWW  (HH*WWD)
#define PLANE (BB*HWW*32)          // elems per 32-ch plane of xn2
#define NLD  1224                  // 18 rows x 2 granules x 34 px staged loads/sub-chunk
#define QSTR (2*34)                // LDS slot stride between q-planes

typedef __attribute__((ext_vector_type(8)))  short  bf16x8;
typedef __attribute__((ext_vector_type(16))) float  f32x16;
typedef __attribute__((ext_vector_type(4)))  unsigned int u32x4;
typedef __attribute__((ext_vector_type(2)))  float  f32x2;

static __device__ __forceinline__ unsigned cvt_pk_bf16(float lo, float hi) {
    unsigned r;
    asm("v_cvt_pk_bf16_f32 %0, %1, %2" : "=v"(r) : "v"(lo), "v"(hi));
    return r;
}
static __device__ __forceinline__ float bf16lo_to_f(unsigned u) {
    union { unsigned u; float f; } c; c.u = u << 16; return c.f;
}
static __device__ __forceinline__ float bf16hi_to_f(unsigned u) {
    union { unsigned u; float f; } c; c.u = u & 0xffff0000u; return c.f;
}

// Repack Wc (OC, Q*C, 3, 3) fp32 -> Wb4, K=16 fragment lane order.
// frag f = (tq*8 + sc)*2 + nt ; lane -> oc = nt*32 + (lane&31),
// c = sc*16 + (lane>>5)*8 + j (j=0..7); tq = tap*3 + q.
__global__ void prep_w(const float* __restrict__ Wc, unsigned short* __restrict__ Wb4) {
    int t = blockIdx.x * 256 + threadIdx.x;       // 27648 tasks, one bf16x8 each
    int lane = t & 63;
    int f    = t >> 6;                            // 0..431
    int nt   = f & 1;
    int sc   = (f >> 1) & 7;
    int tq   = f >> 4;                            // 0..26
    int q    = tq % 3;
    int tap  = tq / 3;
    int oc   = nt * 32 + (lane & 31);
    int cb   = sc * 16 + (lane >> 5) * 8;
    u32x4 o;
    #pragma unroll
    for (int k = 0; k < 4; ++k) {
        float v0 = Wc[(size_t)(oc * 384 + q * 128 + cb + 2 * k) * 9 + tap];
        float v1 = Wc[(size_t)(oc * 384 + q * 128 + cb + 2 * k + 1) * 9 + tap];
        o[k] = cvt_pk_bf16(v0, v1);
    }
    *(u32x4*)(Wb4 + (size_t)t * 8) = o;
}

// Per-pixel LayerNorm over C=128; write xn2 as 4 planes [cc][b][y][x][32ch] bf16
__global__ __launch_bounds__(256) void ln_kernel(
        const float* __restrict__ x, const float* __restrict__ gamma,
        const float* __restrict__ beta, unsigned short* __restrict__ xn2) {
    int p  = blockIdx.x * 256 + threadIdx.x;      // global pixel
    int b  = p >> 16;
    int hw = p & 65535;
    const float* xb = x + (size_t)b * CCH * HWW + hw;
    unsigned buf[64];
    float sum = 0.f, sumsq = 0.f;
    #pragma unroll
    for (int cp = 0; cp < 64; ++cp) {
        float v0 = xb[(size_t)(2 * cp) * HWW];
        float v1 = xb[(size_t)(2 * cp + 1) * HWW];
        sum   += v0 + v1;
        sumsq += v0 * v0 + v1 * v1;
        buf[cp] = cvt_pk_bf16(v0, v1);
    }
    float mu  = sum * (1.f / 128.f);
    float var = sumsq * (1.f / 128.f) - mu * mu;
    float rs  = rsqrtf(var + 1e-5f);
    size_t pix = (size_t)p * 32;
    #pragma unroll
    for (int g = 0; g < 16; ++g) {
        u32x4 o;
        #pragma unroll
        for (int k = 0; k < 4; ++k) {
            int cp = g * 4 + k;
            float f0 = bf16lo_to_f(buf[cp]);
            float f1 = bf16hi_to_f(buf[cp]);
            int c0 = cp * 2, c1 = cp * 2 + 1;
            float y0 = fmaf((f0 - mu) * rs, gamma[c0], beta[c0]);
            float y1 = fmaf((f1 - mu) * rs, gamma[c1], beta[c1]);
            o[k] = cvt_pk_bf16(y0, y1);
        }
        *(u32x4*)(xn2 + (size_t)(g >> 2) * PLANE + pix + (g & 3) * 8) = o;
    }
}

// Implicit-GEMM conv, 32x32x16 MFMA. Block = 16 rows x 32 px x 64 oc; 4 waves,
// wave = 4 rows (M=128) x 64 oc (N=64): acc[4][2]. K-loop = 8 sub-chunks of
// 16 ch; LDS stages powers of an 18x34 halo for one sub-chunk (58.7 KB).
// Per tap: 4 A ds_reads + 2 B loads -> 8 MFMA (LDS 74% / B-L2 25% of matrix).
__global__ __launch_bounds__(256, 2) void conv_kernel(
        const unsigned short* __restrict__ xn2,
        const unsigned short* __restrict__ Wb4,
        float* __restrict__ out) {
    // P[row 18][slot 6 = q*2 + g][px 34][16B] = 58752 B
    __shared__ __align__(16) unsigned char P[18 * 6 * 34 * 16];

    int bid = blockIdx.x;
    int bx  = bid & 7;           // x tile (8)
    int by  = (bid >> 3) & 15;   // y tile (16)
    int b   = bid >> 7;          // batch (8)
    int x0  = bx * 32;
    int y0  = by * 16;
    int tid  = threadIdx.x;
    int lane = tid & 63;
    int w    = tid >> 6;         // wave owns rows {4w..4w+3}
    int l31  = lane & 31;
    int kb   = lane >> 5;        // k-granule bit (8-ch granule within sub-chunk)

    f32x16 acc[4][2];
    #pragma unroll
    for (int mt = 0; mt < 4; ++mt)
        #pragma unroll
        for (int nt = 0; nt < 2; ++nt)
            #pragma unroll
            for (int r = 0; r < 16; ++r)
                acc[mt][nt][r] = 0.f;

    // ---- staging geometry (sub-chunk-invariant): ii = row*68 + g*34 + px ----
    int offg[5];                 // elem offset within a plane (granule part)
    int woff[5];                 // LDS slot index (q=0)
    bool vldf[5], wrf[5];
    #pragma unroll
    for (int it = 0; it < 5; ++it) {
        int item = tid + it * 256;
        bool ok  = item < NLD;
        int ii   = ok ? item : 0;
        int row  = ii / 68;
        int rem  = ii - row * 68;
        int g    = rem / 34;
        int px   = rem - g * 34;
        int yy   = y0 - 1 + row;
        int xx   = x0 - 1 + px;
        bool inb = ok && (unsigned)yy < 256u && (unsigned)xx < 256u;
        offg[it] = (yy * 256 + xx) * 32 + g * 8;
        woff[it] = (row * 6 + g) * 34 + px;
        vldf[it] = inb;
        wrf[it]  = ok;
    }

    const unsigned short* xpb = xn2 + (size_t)b * HWW * 32;
    const bf16x8* wlane = (const bf16x8*)Wb4 + lane;
    // lane part of A slot index: granule kb, px l31
    const unsigned char* pa = P + ((size_t)kb * 34 + l31) * 16;

    // ---- prologue: issue sub-chunk-0 staging loads (plane 0, half 0) ----
    u32x4 rsv[5];
    #pragma unroll
    for (int it = 0; it < 5; ++it) {
        u32x4 v = (u32x4){0u, 0u, 0u, 0u};
        if (vldf[it]) v = *(const u32x4*)(xpb + offg[it]);
        rsv[it] = v;
    }

    #pragma unroll 1
    for (int sc = 0; sc < 8; ++sc) {
        if (sc > 0) __syncthreads();          // all waves done reading prev sub-chunk
        // ---- write powers to LDS from staged regs ----
        #pragma unroll
        for (int it = 0; it < 5; ++it) {
            if (!wrf[it]) continue;
            u32x4 u1 = rsv[it];
            u32x4 u2, u3;
            #pragma unroll
            for (int k = 0; k < 4; ++k) {
                float f0 = bf16lo_to_f(u1[k]);
                float f1 = bf16hi_to_f(u1[k]);
                float s0 = f0 * f0, s1 = f1 * f1;
                u2[k] = cvt_pk_bf16(s0, s1);
                u3[k] = cvt_pk_bf16(s0 * f0, s1 * f1);
            }
            unsigned char* cell = P + (size_t)woff[it] * 16;
            *(u32x4*)(cell)                  = u1;   // q=0
            *(u32x4*)(cell + QSTR * 16)      = u2;   // q=1
            *(u32x4*)(cell + 2 * QSTR * 16)  = u3;   // q=2
        }
        __syncthreads();

        // ---- issue sub-chunk sc+1 staging loads (fly under the MFMAs) ----
        if (sc < 7) {
            const int scn = sc + 1;
            const unsigned short* xpn = xpb + (size_t)(scn >> 1) * PLANE
                                            + (scn & 1) * 16;
            #pragma unroll
            for (int it = 0; it < 5; ++it) {
                u32x4 v = (u32x4){0u, 0u, 0u, 0u};
                if (vldf[it]) v = *(const u32x4*)(xpn + offg[it]);
                rsv[it] = v;
            }
        }

        // ---- 27 taps, software-pipelined A/B fragment prefetch ----
        const bf16x8* wsc = wlane + (size_t)sc * 2 * 64;   // + tq*16*64
        bf16x8 av[2][4], bv[2][2];
        #pragma unroll
        for (int mt = 0; mt < 4; ++mt)
            av[0][mt] = *(const bf16x8*)(pa + (size_t)((4 * w + mt) * 6 * 34) * 16);
        #pragma unroll
        for (int nt = 0; nt < 2; ++nt)
            bv[0][nt] = wsc[nt * 64];

        #pragma unroll
        for (int tq = 0; tq < 27; ++tq) {
            const int cur = tq & 1, nxt = cur ^ 1;
            if (tq < 26) {
                const int t2 = tq + 1;
                const int ky = t2 / 9, kx = (t2 / 3) % 3, q = t2 % 3;
                #pragma unroll
                for (int mt = 0; mt < 4; ++mt)
                    av[nxt][mt] = *(const bf16x8*)(pa
                        + (size_t)(((4 * w + mt + ky) * 6 + q * 2) * 34 + kx) * 16);
                #pragma unroll
                for (int nt = 0; nt < 2; ++nt)
                    bv[nxt][nt] = wsc[((size_t)t2 * 16 + nt) * 64];
            }
            __builtin_amdgcn_s_setprio(1);
            #pragma unroll
            for (int nt = 0; nt < 2; ++nt)
                #pragma unroll
                for (int mt = 0; mt < 4; ++mt)
                    acc[mt][nt] = __builtin_amdgcn_mfma_f32_32x32x16_bf16(
                        av[cur][mt], bv[cur][nt], acc[mt][nt], 0, 0, 0);
            __builtin_amdgcn_s_setprio(0);
        }
    }

    // ---- epilogue: fused PixelUnshuffle(2) ----
    // C/D 32x32: col(oc) = lane&31, row(px) = (reg&3) + 8*(reg>>2) + 4*(lane>>5)
    #pragma unroll
    for (int mt = 0; mt < 4; ++mt) {
        int y  = y0 + 4 * w + mt;
        int s  = mt & 1;                 // y&1 (y0, 4w even)
        int y2 = y >> 1;
        #pragma unroll
        for (int nt = 0; nt < 2; ++nt) {
            int oc = nt * 32 + l31;
            #pragma unroll
            for (int p = 0; p < 8; ++p) {
                const int r  = (p & 1) + (p >> 1) * 4;       // 0,1,4,5,8,9,12,13
                int px = (r & 3) + 8 * (r >> 2) + 4 * kb;
                int x  = x0 + px;
                int ch = oc * 4 + s * 2 + (x & 1);
                int x2 = x >> 1;
                size_t off = ((size_t)(b * 256 + ch) * 128 + y2) * 128 + x2;
                f32x2 v;
                v.x = acc[mt][nt][r];
                v.y = acc[mt][nt][r + 2];
                *(f32x2*)(out + off) = v;
            }
        }
    }
}

extern "C" void kernel_launch(void* const* d_in, const int* in_sizes, int n_in,
                              void* d_out, int out_size, void* d_ws, size_t ws_size,
                              hipStream_t stream) {
    const float* x     = (const float*)d_in[0];
    const float* gamma = (const float*)d_in[1];
    const float* beta  = (const float*)d_in[2];
    const float* Wc    = (const float*)d_in[3];
    float* out = (float*)d_out;

    const size_t xn_bytes = (size_t)4 * PLANE * 2;               // 134217728
    const size_t wb_bytes = (size_t)27648 * 16;                  // 442368
    if (ws_size < xn_bytes + wb_bytes) return;                   // visible failure
    unsigned short* xn2 = (unsigned short*)d_ws;
    unsigned short* Wb4 = (unsigned short*)((char*)d_ws + xn_bytes);

    hipLaunchKernelGGL(prep_w, dim3(108), dim3(256), 0, stream, Wc, Wb4);
    hipLaunchKernelGGL(ln_kernel, dim3(2048), dim3(256), 0, stream, x, gamma, beta, xn2);
    hipLaunchKernelGGL(conv_kernel, dim3(1024), dim3(256), 0, stream, xn2, Wb4, out);
}